// Round 1
// baseline (3991.256 us; speedup 1.0000x reference)
//
#include <hip/hip_runtime.h>
#include <hip/hip_bf16.h>
#include <float.h>

#define NROW 131072

// ---------------------------------------------------------------------------
// Tiled f32 GEMM: C = act(A @ W + bias), A: MxK row-major, W: KxN row-major.
// BM=128 rows/block, BN=128 or 64 cols/block, BK=16, 256 threads,
// each thread computes TM x TN outputs (8x8 or 8x4) via LDS outer product.
// Column/row ownership is split (tx*4 and 64+tx*4) so LDS reads are
// 16B-strided -> 2-way bank aliasing (free on CDNA4).
// ---------------------------------------------------------------------------
template<int BM, int BN, int BK, int TM, int TN>
__global__ __launch_bounds__(256) void gemm_bias_act(
    const float* __restrict__ A, const float* __restrict__ W,
    const float* __restrict__ bias, float* __restrict__ C,
    int M, int K, int Ncol, int relu)
{
    __shared__ float As[BK][BM];
    __shared__ float Bs[BK][BN];

    const int tid = threadIdx.x;
    const int tx = tid & 15;        // 16 col groups
    const int ty = tid >> 4;        // 16 row groups
    const int bm = blockIdx.y * BM;
    const int bn = blockIdx.x * BN;

    float acc[TM][TN];
#pragma unroll
    for (int i = 0; i < TM; ++i)
#pragma unroll
        for (int j = 0; j < TN; ++j) acc[i][j] = 0.f;

    for (int k0 = 0; k0 < K; k0 += BK) {
        // ---- load A tile (BM x BK), store transposed As[k][m]
#pragma unroll
        for (int f = tid; f < BM * BK / 4; f += 256) {
            int r  = f / (BK / 4);
            int c4 = (f % (BK / 4)) * 4;
            float4 v = *reinterpret_cast<const float4*>(
                &A[(size_t)(bm + r) * K + k0 + c4]);
            As[c4 + 0][r] = v.x;
            As[c4 + 1][r] = v.y;
            As[c4 + 2][r] = v.z;
            As[c4 + 3][r] = v.w;
        }
        // ---- load B tile (BK x BN) directly
#pragma unroll
        for (int f = tid; f < BK * BN / 4; f += 256) {
            int r  = f / (BN / 4);
            int c4 = (f % (BN / 4)) * 4;
            *reinterpret_cast<float4*>(&Bs[r][c4]) =
                *reinterpret_cast<const float4*>(
                    &W[(size_t)(k0 + r) * Ncol + bn + c4]);
        }
        __syncthreads();

#pragma unroll
        for (int kk = 0; kk < BK; ++kk) {
            float a[TM], b[TN];
#pragma unroll
            for (int i = 0; i < 4; ++i) a[i] = As[kk][ty * 4 + i];
#pragma unroll
            for (int i = 4; i < TM; ++i) a[i] = As[kk][64 + ty * 4 + (i - 4)];
#pragma unroll
            for (int j = 0; j < 4 && j < TN; ++j) b[j] = Bs[kk][tx * 4 + j];
            if constexpr (TN == 8) {
#pragma unroll
                for (int j = 4; j < 8; ++j) b[j] = Bs[kk][64 + tx * 4 + (j - 4)];
            }
#pragma unroll
            for (int i = 0; i < TM; ++i)
#pragma unroll
                for (int j = 0; j < TN; ++j)
                    acc[i][j] = fmaf(a[i], b[j], acc[i][j]);
        }
        __syncthreads();
    }

    // ---- epilogue: bias + optional relu, vectorized float4 stores
#pragma unroll
    for (int i = 0; i < TM; ++i) {
        int rloc = (i < 4) ? (ty * 4 + i) : (64 + ty * 4 + (i - 4));
        size_t row = (size_t)(bm + rloc);
#pragma unroll
        for (int jh = 0; jh < TN / 4; ++jh) {
            int col = bn + jh * 64 + tx * 4;
            float4 v;
            v.x = acc[i][jh * 4 + 0] + bias[col + 0];
            v.y = acc[i][jh * 4 + 1] + bias[col + 1];
            v.z = acc[i][jh * 4 + 2] + bias[col + 2];
            v.w = acc[i][jh * 4 + 3] + bias[col + 3];
            if (relu) {
                v.x = fmaxf(v.x, 0.f); v.y = fmaxf(v.y, 0.f);
                v.z = fmaxf(v.z, 0.f); v.w = fmaxf(v.w, 0.f);
            }
            *reinterpret_cast<float4*>(&C[row * Ncol + col]) = v;
        }
    }
}

// ---------------------------------------------------------------------------
// One residual-quantization level.
// Each thread owns one row: r (64 f32) in registers, codebook (256x64) in
// LDS (broadcast reads). argmin_c ||r||^2 - 2 r.c + ||c||^2  ==
// argmin_c (cnorm[c] - 2 dot) (strict < keeps first occurrence like argmin).
// Updates resid in place, accumulates xq, writes index (as float),
// atomically accumulates sum((r - e)^2) for the loss.
// ---------------------------------------------------------------------------
__global__ __launch_bounds__(256) void quantize_level(
    float* __restrict__ resid, const float* __restrict__ cb,
    float* __restrict__ xq, float* __restrict__ idx_out,
    float* __restrict__ loss_acc, int level, int first)
{
    __shared__ float cbs[256 * 64];
    __shared__ float cnorm[256];

    const int tid = threadIdx.x;

    // stage codebook
    for (int i = tid; i < 256 * 64 / 4; i += 256)
        reinterpret_cast<float4*>(cbs)[i] =
            reinterpret_cast<const float4*>(cb)[i];
    __syncthreads();

    // per-code squared norms (one code per thread; one-off cost)
    {
        const float4* c = reinterpret_cast<const float4*>(&cbs[tid * 64]);
        float s0 = 0.f, s1 = 0.f, s2 = 0.f, s3 = 0.f;
#pragma unroll
        for (int q = 0; q < 16; q += 4) {
            float4 v0 = c[q], v1 = c[q + 1], v2 = c[q + 2], v3 = c[q + 3];
            s0 += v0.x * v0.x + v0.y * v0.y + v0.z * v0.z + v0.w * v0.w;
            s1 += v1.x * v1.x + v1.y * v1.y + v1.z * v1.z + v1.w * v1.w;
            s2 += v2.x * v2.x + v2.y * v2.y + v2.z * v2.z + v2.w * v2.w;
            s3 += v3.x * v3.x + v3.y * v3.y + v3.z * v3.z + v3.w * v3.w;
        }
        cnorm[tid] = (s0 + s1) + (s2 + s3);
    }
    __syncthreads();

    const size_t row = (size_t)blockIdx.x * 256 + tid;
    float4 r[16];
    {
        const float4* rg = reinterpret_cast<const float4*>(&resid[row * 64]);
#pragma unroll
        for (int q = 0; q < 16; ++q) r[q] = rg[q];
    }

    float dmin = FLT_MAX;
    int best = 0;
    for (int c = 0; c < 256; ++c) {
        const float4* cv = reinterpret_cast<const float4*>(&cbs[c * 64]);
        float s0 = 0.f, s1 = 0.f, s2 = 0.f, s3 = 0.f;
#pragma unroll
        for (int q = 0; q < 16; q += 4) {
            float4 c0 = cv[q], c1 = cv[q + 1], c2 = cv[q + 2], c3 = cv[q + 3];
            s0 += r[q].x     * c0.x + r[q].y     * c0.y + r[q].z     * c0.z + r[q].w     * c0.w;
            s1 += r[q + 1].x * c1.x + r[q + 1].y * c1.y + r[q + 1].z * c1.z + r[q + 1].w * c1.w;
            s2 += r[q + 2].x * c2.x + r[q + 2].y * c2.y + r[q + 2].z * c2.z + r[q + 2].w * c2.w;
            s3 += r[q + 3].x * c3.x + r[q + 3].y * c3.y + r[q + 3].z * c3.z + r[q + 3].w * c3.w;
        }
        float d = cnorm[c] - 2.f * ((s0 + s1) + (s2 + s3));
        if (d < dmin) { dmin = d; best = c; }
    }

    // update residual / xq / loss
    float lsum = 0.f;
    {
        const float4* ev = reinterpret_cast<const float4*>(&cbs[best * 64]);
        float4* rg = reinterpret_cast<float4*>(&resid[row * 64]);
        float4* xw = reinterpret_cast<float4*>(&xq[row * 64]);
#pragma unroll
        for (int q = 0; q < 16; ++q) {
            float4 e = ev[q];
            float4 rn;
            rn.x = r[q].x - e.x; rn.y = r[q].y - e.y;
            rn.z = r[q].z - e.z; rn.w = r[q].w - e.w;
            lsum += rn.x * rn.x + rn.y * rn.y + rn.z * rn.z + rn.w * rn.w;
            rg[q] = rn;
            if (first) {
                xw[q] = e;
            } else {
                float4 xv = xw[q];
                xv.x += e.x; xv.y += e.y; xv.z += e.z; xv.w += e.w;
                xw[q] = xv;
            }
        }
    }
    idx_out[row * 4 + level] = (float)best;

    // wave reduce + one atomic per wave
#pragma unroll
    for (int off = 32; off > 0; off >>= 1)
        lsum += __shfl_down(lsum, off);
    if ((tid & 63) == 0) atomicAdd(loss_acc, lsum);
}

__global__ void finalize_loss(const float* __restrict__ loss4,
                              float* __restrict__ rq)
{
    if (threadIdx.x == 0) {
        float s = loss4[0] + loss4[1] + loss4[2] + loss4[3];
        // per level: loss = (1+BETA) * sum / (N*64);  rq = mean over 4 levels
        rq[0] = 1.25f * s / (4.0f * (float)NROW * 64.0f);
    }
}

extern "C" void kernel_launch(void* const* d_in, const int* in_sizes, int n_in,
                              void* d_out, int out_size, void* d_ws, size_t ws_size,
                              hipStream_t stream)
{
    const float* ew0 = (const float*)d_in[0];
    const float* eb0 = (const float*)d_in[1];
    const float* ew1 = (const float*)d_in[2];
    const float* eb1 = (const float*)d_in[3];
    const float* ew2 = (const float*)d_in[4];
    const float* eb2 = (const float*)d_in[5];
    const float* dw0 = (const float*)d_in[6];
    const float* db0 = (const float*)d_in[7];
    const float* dw1 = (const float*)d_in[8];
    const float* db1 = (const float*)d_in[9];
    const float* dw2 = (const float*)d_in[10];
    const float* db2 = (const float*)d_in[11];
    const float* cb  = (const float*)d_in[12];
    const float* x   = (const float*)d_in[13];

    const size_t N = NROW;
    float* ws    = (float*)d_ws;
    float* h1    = ws;                  // N*512
    float* h2    = h1 + N * 512;        // N*256
    float* z     = h2 + N * 256;        // N*64 (becomes residual in place)
    float* xq    = z  + N * 64;         // N*64
    float* loss4 = xq + N * 64;         // 4 floats

    float* out  = (float*)d_out;        // N*768
    float* rq   = out + N * 768;        // 1
    float* idxf = rq + 1;               // N*4 (indices written as float)

    hipMemsetAsync(loss4, 0, 4 * sizeof(float), stream);

    dim3 blk(256);
    // encoder
    gemm_bias_act<128,128,16,8,8><<<dim3(512/128, N/128), blk, 0, stream>>>(
        x,  ew0, eb0, h1, (int)N, 768, 512, 1);
    gemm_bias_act<128,128,16,8,8><<<dim3(256/128, N/128), blk, 0, stream>>>(
        h1, ew1, eb1, h2, (int)N, 512, 256, 1);
    gemm_bias_act<128, 64,16,8,4><<<dim3(64/64,  N/128), blk, 0, stream>>>(
        h2, ew2, eb2, z,  (int)N, 256,  64, 0);

    // residual quantization, 4 levels
    for (int l = 0; l < 4; ++l) {
        quantize_level<<<dim3(N / 256), blk, 0, stream>>>(
            z, cb + (size_t)l * 256 * 64, xq, idxf, loss4 + l, l, l == 0 ? 1 : 0);
    }
    finalize_loss<<<dim3(1), dim3(64), 0, stream>>>(loss4, rq);

    // decoder (reuse h2 then h1 as scratch)
    gemm_bias_act<128,128,16,8,8><<<dim3(256/128, N/128), blk, 0, stream>>>(
        xq, dw0, db0, h2, (int)N,  64, 256, 1);
    gemm_bias_act<128,128,16,8,8><<<dim3(512/128, N/128), blk, 0, stream>>>(
        h2, dw1, db1, h1, (int)N, 256, 512, 1);
    gemm_bias_act<128,128,16,8,8><<<dim3(768/128, N/128), blk, 0, stream>>>(
        h1, dw2, db2, out, (int)N, 512, 768, 0);
}

// Round 2
// 1991.480 us; speedup vs baseline: 2.0042x; 2.0042x over previous
//
#include <hip/hip_runtime.h>
#include <hip/hip_bf16.h>
#include <float.h>
#include <type_traits>

#define NROW 131072

using f16x8 = __attribute__((ext_vector_type(8))) _Float16;
using f16x4 = __attribute__((ext_vector_type(4))) _Float16;
using s16x8 = __attribute__((ext_vector_type(8))) short;
using f32x4 = __attribute__((ext_vector_type(4))) float;

__device__ __forceinline__ f32x4 mfma32(f16x8 a, f16x8 b, f32x4 c) {
    return __builtin_amdgcn_mfma_f32_16x16x32_f16(a, b, c, 0, 0, 0);
}
__device__ __forceinline__ f32x4 mfma32(s16x8 a, s16x8 b, f32x4 c) {
    return __builtin_amdgcn_mfma_f32_16x16x32_bf16(a, b, c, 0, 0, 0);
}

__device__ __forceinline__ short f2bf(float f) {
    unsigned u = __builtin_bit_cast(unsigned, f);
    u += 0x7fffu + ((u >> 16) & 1u);
    return (short)(u >> 16);
}
__device__ __forceinline__ float bf2f(short s) {
    unsigned u = ((unsigned)(unsigned short)s) << 16;
    return __builtin_bit_cast(float, u);
}

__device__ __forceinline__ void gload16(const void* g, void* l) {
    __builtin_amdgcn_global_load_lds(
        (const __attribute__((address_space(1))) void*)g,
        (__attribute__((address_space(3))) void*)l, 16, 0, 0);
}

// ---------------------------------------------------------------------------
// MFMA GEMM: C = act(A @ Bt^T + bias).  A: [M][K] ET row-major,
// Bt: [N][K] ET row-major (pre-transposed weights).
// SPLIT: A/B given as hi + lo*2^-12 (lo stored pre-scaled by 4096),
//        acc2 accumulates the scaled cross terms, epilogue adds acc2/4096.
// OUT: 0 = f32, 1 = fp16 hi/lo split (pre-scaled lo), 2 = bf16.
// 256 threads, 2x2 waves, wave tile (BM/2)x(BN/2), 16x16x32 MFMA.
// Staging via global_load_lds width-16, linear LDS layout [row][BK].
// ---------------------------------------------------------------------------
template<typename ET, bool SPLIT, int OUT, int BM, int BN, int BK, bool RELU>
__global__ __launch_bounds__(256) void mm_mfma(
    const ET* __restrict__ Ah, const ET* __restrict__ Al,
    const ET* __restrict__ Bh, const ET* __restrict__ Bl,
    const float* __restrict__ bias,
    void* __restrict__ O0, void* __restrict__ O1,
    int M, int N, int K)
{
    constexpr int WTM = BM / 2, WTN = BN / 2;
    constexpr int MF = WTM / 16, NF = WTN / 16;
    constexpr int KS = BK / 32;
    using VT = typename std::conditional<std::is_same<ET, _Float16>::value,
                                         f16x8, s16x8>::type;

    __shared__ __align__(16) ET lah[BM * BK];
    __shared__ __align__(16) ET lal[SPLIT ? BM * BK : 1];
    __shared__ __align__(16) ET lbh[BN * BK];
    __shared__ __align__(16) ET lbl[SPLIT ? BN * BK : 1];

    const int tid  = threadIdx.x;
    const int lane = tid & 63;
    const int wave = tid >> 6;
    const int wm = wave >> 1, wn = wave & 1;
    const int bm = blockIdx.y * BM;
    const int bn = blockIdx.x * BN;

    constexpr int IA  = BM * BK * 2 / 1024;   // 1-KB staging insts, A tile
    constexpr int IB  = BN * BK * 2 / 1024;
    constexpr int LPR = BK / 8;               // lanes per row
    constexpr int RPI = 64 / LPR;             // rows per inst

    const ET* src; ET* lbase; int row0, inst0, insts;
    if constexpr (SPLIT) {
        if      (wave == 0) { src = Ah; lbase = lah; row0 = bm; inst0 = 0; insts = IA; }
        else if (wave == 1) { src = Al; lbase = lal; row0 = bm; inst0 = 0; insts = IA; }
        else if (wave == 2) { src = Bh; lbase = lbh; row0 = bn; inst0 = 0; insts = IB; }
        else                { src = Bl; lbase = lbl; row0 = bn; inst0 = 0; insts = IB; }
    } else {
        if (wave < 2) { src = Ah; lbase = lah; row0 = bm; inst0 = (wave & 1) * (IA / 2); insts = IA / 2; }
        else          { src = Bh; lbase = lbh; row0 = bn; inst0 = (wave & 1) * (IB / 2); insts = IB / 2; }
    }
    const int srow = lane / LPR;
    const int skel = (lane % LPR) * 8;

    f32x4 acc1[MF][NF];
    f32x4 acc2[SPLIT ? MF : 1][SPLIT ? NF : 1];
#pragma unroll
    for (int m = 0; m < MF; ++m)
#pragma unroll
        for (int n = 0; n < NF; ++n) {
            acc1[m][n] = f32x4{0.f, 0.f, 0.f, 0.f};
            if constexpr (SPLIT) acc2[m][n] = f32x4{0.f, 0.f, 0.f, 0.f};
        }

    for (int k0 = 0; k0 < K; k0 += BK) {
        for (int i = 0; i < insts; ++i) {
            int inst = inst0 + i;
            int row  = inst * RPI + srow;
            gload16(src + (size_t)(row0 + row) * K + k0 + skel,
                    lbase + inst * 512);
        }
        __syncthreads();

#pragma unroll
        for (int ks = 0; ks < KS; ++ks) {
            const int ko = ks * 32 + (lane >> 4) * 8;
            VT bh_[NF]; VT bl_[SPLIT ? NF : 1];
#pragma unroll
            for (int n = 0; n < NF; ++n) {
                int nr = wn * WTN + n * 16 + (lane & 15);
                bh_[n] = *(const VT*)&lbh[nr * BK + ko];
                if constexpr (SPLIT) bl_[n] = *(const VT*)&lbl[nr * BK + ko];
            }
#pragma unroll
            for (int m = 0; m < MF; ++m) {
                int mr = wm * WTM + m * 16 + (lane & 15);
                VT a_h = *(const VT*)&lah[mr * BK + ko];
                VT a_l;
                if constexpr (SPLIT) a_l = *(const VT*)&lal[mr * BK + ko];
#pragma unroll
                for (int n = 0; n < NF; ++n) {
                    acc1[m][n] = mfma32(a_h, bh_[n], acc1[m][n]);
                    if constexpr (SPLIT) {
                        acc2[m][n] = mfma32(a_l, bh_[n], acc2[m][n]);
                        acc2[m][n] = mfma32(a_h, bl_[n], acc2[m][n]);
                    }
                }
            }
        }
        __syncthreads();
    }

#pragma unroll
    for (int m = 0; m < MF; ++m)
#pragma unroll
        for (int n = 0; n < NF; ++n) {
            int col = bn + wn * WTN + n * 16 + (lane & 15);
            float bv = bias[col];
            int rbase = bm + wm * WTM + m * 16 + (lane >> 4) * 4;
            f32x4 v = acc1[m][n];
            if constexpr (SPLIT) {
                f32x4 v2 = acc2[m][n];
#pragma unroll
                for (int r = 0; r < 4; ++r) v[r] += v2[r] * (1.0f / 4096.0f);
            }
#pragma unroll
            for (int r = 0; r < 4; ++r) {
                float f = v[r] + bv;
                if constexpr (RELU) f = fmaxf(f, 0.f);
                size_t off = (size_t)(rbase + r) * N + col;
                if constexpr (OUT == 0) {
                    ((float*)O0)[off] = f;
                } else if constexpr (OUT == 1) {
                    _Float16 hi = (_Float16)f;
                    _Float16 lo = (_Float16)((f - (float)hi) * 4096.f);
                    ((_Float16*)O0)[off] = hi;
                    ((_Float16*)O1)[off] = lo;
                } else {
                    ((short*)O0)[off] = f2bf(f);
                }
            }
        }
}

// ---------------------------------------------------------------------------
// x (f32) -> xh, xl (fp16, lo pre-scaled by 4096)
// ---------------------------------------------------------------------------
__global__ __launch_bounds__(256) void prep_x(
    const float* __restrict__ x, _Float16* __restrict__ xh, _Float16* __restrict__ xl)
{
    const size_t total = (size_t)NROW * 768 / 4;
    for (size_t i = (size_t)blockIdx.x * 256 + threadIdx.x; i < total;
         i += (size_t)gridDim.x * 256) {
        float4 v = ((const float4*)x)[i];
        f16x4 h, l;
        h[0] = (_Float16)v.x; h[1] = (_Float16)v.y;
        h[2] = (_Float16)v.z; h[3] = (_Float16)v.w;
        l[0] = (_Float16)((v.x - (float)h[0]) * 4096.f);
        l[1] = (_Float16)((v.y - (float)h[1]) * 4096.f);
        l[2] = (_Float16)((v.z - (float)h[2]) * 4096.f);
        l[3] = (_Float16)((v.w - (float)h[3]) * 4096.f);
        ((f16x4*)xh)[i] = h;
        ((f16x4*)xl)[i] = l;
    }
}

// ---------------------------------------------------------------------------
// W [K][N] f32 -> transposed Th/Tl [N][K] (fp16 split or bf16)
// ---------------------------------------------------------------------------
template<bool SPLIT>
__global__ __launch_bounds__(256) void prep_w(
    const float* __restrict__ W, void* __restrict__ Th, void* __restrict__ Tl,
    int K, int N)
{
    __shared__ float t[32][33];
    const int bn = blockIdx.x * 32, bk = blockIdx.y * 32;
    const int lx = threadIdx.x & 31, ly = threadIdx.x >> 5;
#pragma unroll
    for (int i = 0; i < 32; i += 8)
        t[ly + i][lx] = W[(size_t)(bk + ly + i) * N + bn + lx];
    __syncthreads();
#pragma unroll
    for (int i = 0; i < 32; i += 8) {
        float v = t[lx][ly + i];
        size_t o = (size_t)(bn + ly + i) * K + bk + lx;
        if constexpr (SPLIT) {
            _Float16 hi = (_Float16)v;
            _Float16 lo = (_Float16)((v - (float)hi) * 4096.f);
            ((_Float16*)Th)[o] = hi;
            ((_Float16*)Tl)[o] = lo;
        } else {
            ((short*)Th)[o] = f2bf(v);
        }
    }
}

// ---------------------------------------------------------------------------
// Fused 4-level residual quantization. One thread per row; residual and xq
// stay in registers; codebook of the current level staged in LDS.
// Writes xq as bf16, indices as float, accumulates total sq-residual.
// ---------------------------------------------------------------------------
__global__ __launch_bounds__(256) void rq_fused(
    const float* __restrict__ z, const float* __restrict__ cb,
    short* __restrict__ xqb, float* __restrict__ idx_out,
    float* __restrict__ loss1)
{
    __shared__ float cbs[256 * 64];
    __shared__ float cnorm[256];
    const int tid = threadIdx.x;
    const size_t row = (size_t)blockIdx.x * 256 + tid;

    float4 r[16], xa[16];
    {
        const float4* rg = (const float4*)(z + row * 64);
#pragma unroll
        for (int q = 0; q < 16; ++q) {
            r[q] = rg[q];
            xa[q] = float4{0.f, 0.f, 0.f, 0.f};
        }
    }

    float lsum = 0.f;
    for (int l = 0; l < 4; ++l) {
        __syncthreads();   // previous level finished with cbs
        {
            const float4* csrc = (const float4*)(cb + (size_t)l * 16384);
            for (int i = tid; i < 4096; i += 256)
                ((float4*)cbs)[i] = csrc[i];
        }
        __syncthreads();
        {
            const float4* c = (const float4*)(&cbs[tid * 64]);
            float s0 = 0.f, s1 = 0.f, s2 = 0.f, s3 = 0.f;
#pragma unroll
            for (int q = 0; q < 16; q += 4) {
                float4 v0 = c[q], v1 = c[q + 1], v2 = c[q + 2], v3 = c[q + 3];
                s0 += v0.x * v0.x + v0.y * v0.y + v0.z * v0.z + v0.w * v0.w;
                s1 += v1.x * v1.x + v1.y * v1.y + v1.z * v1.z + v1.w * v1.w;
                s2 += v2.x * v2.x + v2.y * v2.y + v2.z * v2.z + v2.w * v2.w;
                s3 += v3.x * v3.x + v3.y * v3.y + v3.z * v3.z + v3.w * v3.w;
            }
            cnorm[tid] = (s0 + s1) + (s2 + s3);
        }
        __syncthreads();

        float dmin = FLT_MAX;
        int best = 0;
        for (int c = 0; c < 256; ++c) {
            const float4* cv = (const float4*)(&cbs[c * 64]);
            float s0 = 0.f, s1 = 0.f, s2 = 0.f, s3 = 0.f;
#pragma unroll
            for (int q = 0; q < 16; q += 4) {
                float4 c0 = cv[q], c1 = cv[q + 1], c2 = cv[q + 2], c3 = cv[q + 3];
                s0 += r[q].x     * c0.x + r[q].y     * c0.y + r[q].z     * c0.z + r[q].w     * c0.w;
                s1 += r[q + 1].x * c1.x + r[q + 1].y * c1.y + r[q + 1].z * c1.z + r[q + 1].w * c1.w;
                s2 += r[q + 2].x * c2.x + r[q + 2].y * c2.y + r[q + 2].z * c2.z + r[q + 2].w * c2.w;
                s3 += r[q + 3].x * c3.x + r[q + 3].y * c3.y + r[q + 3].z * c3.z + r[q + 3].w * c3.w;
            }
            float d = cnorm[c] - 2.f * ((s0 + s1) + (s2 + s3));
            if (d < dmin) { dmin = d; best = c; }
        }

        const float4* ev = (const float4*)(&cbs[best * 64]);
#pragma unroll
        for (int q = 0; q < 16; ++q) {
            float4 e = ev[q];
            r[q].x -= e.x; r[q].y -= e.y; r[q].z -= e.z; r[q].w -= e.w;
            xa[q].x += e.x; xa[q].y += e.y; xa[q].z += e.z; xa[q].w += e.w;
            lsum += r[q].x * r[q].x + r[q].y * r[q].y
                  + r[q].z * r[q].z + r[q].w * r[q].w;
        }
        idx_out[row * 4 + l] = (float)best;
    }

    // emit xq as bf16 (decoder tolerance is huge)
    {
        short xb[64];
#pragma unroll
        for (int q = 0; q < 16; ++q) {
            xb[q * 4 + 0] = f2bf(xa[q].x);
            xb[q * 4 + 1] = f2bf(xa[q].y);
            xb[q * 4 + 2] = f2bf(xa[q].z);
            xb[q * 4 + 3] = f2bf(xa[q].w);
        }
        s16x8* dst = (s16x8*)(xqb + row * 64);
#pragma unroll
        for (int q = 0; q < 8; ++q) dst[q] = ((s16x8*)xb)[q];
    }

#pragma unroll
    for (int off = 32; off > 0; off >>= 1)
        lsum += __shfl_down(lsum, off);
    if ((tid & 63) == 0) atomicAdd(loss1, lsum);
}

__global__ void finalize_loss(const float* __restrict__ loss1, float* __restrict__ rq)
{
    if (threadIdx.x == 0)
        rq[0] = 1.25f * loss1[0] / (4.0f * (float)NROW * 64.0f);
}

extern "C" void kernel_launch(void* const* d_in, const int* in_sizes, int n_in,
                              void* d_out, int out_size, void* d_ws, size_t ws_size,
                              hipStream_t stream)
{
    const float* ew0 = (const float*)d_in[0];
    const float* eb0 = (const float*)d_in[1];
    const float* ew1 = (const float*)d_in[2];
    const float* eb1 = (const float*)d_in[3];
    const float* ew2 = (const float*)d_in[4];
    const float* eb2 = (const float*)d_in[5];
    const float* dw0 = (const float*)d_in[6];
    const float* db0 = (const float*)d_in[7];
    const float* dw1 = (const float*)d_in[8];
    const float* db1 = (const float*)d_in[9];
    const float* dw2 = (const float*)d_in[10];
    const float* db2 = (const float*)d_in[11];
    const float* cb  = (const float*)d_in[12];
    const float* x   = (const float*)d_in[13];

    const size_t N = NROW;
    char* w = (char*)d_ws;
    _Float16* h1h = (_Float16*)w;                 w += N * 512 * 2;
    _Float16* h1l = (_Float16*)w;                 w += N * 512 * 2;
    _Float16* h2h = (_Float16*)w;                 w += N * 256 * 2;
    _Float16* h2l = (_Float16*)w;                 w += N * 256 * 2;
    float*    z   = (float*)w;                    w += N * 64 * 4;
    short*    xqb = (short*)w;                    w += N * 64 * 2;
    _Float16* we0h = (_Float16*)w;                w += 512 * 768 * 2;
    _Float16* we0l = (_Float16*)w;                w += 512 * 768 * 2;
    _Float16* we1h = (_Float16*)w;                w += 256 * 512 * 2;
    _Float16* we1l = (_Float16*)w;                w += 256 * 512 * 2;
    _Float16* we2h = (_Float16*)w;                w += 64 * 256 * 2;
    _Float16* we2l = (_Float16*)w;                w += 64 * 256 * 2;
    short*    wd0  = (short*)w;                   w += 256 * 64 * 2;
    short*    wd1  = (short*)w;                   w += 512 * 256 * 2;
    short*    wd2  = (short*)w;                   w += 768 * 512 * 2;
    float*    loss1 = (float*)w;                  w += 256;

    float* out  = (float*)d_out;                  // N*768
    float* rq   = out + N * 768;                  // 1
    float* idxf = rq + 1;                         // N*4

    // x hi/lo live in the (not-yet-written) out region: exactly N*768*4 bytes
    _Float16* xh = (_Float16*)d_out;
    _Float16* xl = xh + N * 768;

    hipMemsetAsync(loss1, 0, sizeof(float), stream);

    dim3 blk(256);
    prep_x<<<dim3(2048), blk, 0, stream>>>(x, xh, xl);
    prep_w<true ><<<dim3(512/32, 768/32), blk, 0, stream>>>(ew0, we0h, we0l, 768, 512);
    prep_w<true ><<<dim3(256/32, 512/32), blk, 0, stream>>>(ew1, we1h, we1l, 512, 256);
    prep_w<true ><<<dim3( 64/32, 256/32), blk, 0, stream>>>(ew2, we2h, we2l, 256,  64);
    prep_w<false><<<dim3(256/32,  64/32), blk, 0, stream>>>(dw0, wd0, nullptr,  64, 256);
    prep_w<false><<<dim3(512/32, 256/32), blk, 0, stream>>>(dw1, wd1, nullptr, 256, 512);
    prep_w<false><<<dim3(768/32, 512/32), blk, 0, stream>>>(dw2, wd2, nullptr, 512, 768);

    // encoder: fp16-split MFMA
    mm_mfma<_Float16, true, 1, 128, 128, 32, true ><<<dim3(4, N/128), blk, 0, stream>>>(
        xh, xl, we0h, we0l, eb0, h1h, h1l, (int)N, 512, 768);
    mm_mfma<_Float16, true, 1, 128, 128, 32, true ><<<dim3(2, N/128), blk, 0, stream>>>(
        h1h, h1l, we1h, we1l, eb1, h2h, h2l, (int)N, 256, 512);
    mm_mfma<_Float16, true, 0, 128,  64, 32, false><<<dim3(1, N/128), blk, 0, stream>>>(
        h2h, h2l, we2h, we2l, eb2, z, nullptr, (int)N, 64, 256);

    // fused residual quantization
    rq_fused<<<dim3(N/256), blk, 0, stream>>>(z, cb, xqb, idxf, loss1);
    finalize_loss<<<dim3(1), dim3(64), 0, stream>>>(loss1, rq);

    // decoder: bf16 MFMA (reuse h2h / h1h buffers as bf16)
    short* h2b = (short*)h2h;
    short* h1b = (short*)h1h;
    mm_mfma<short, false, 2, 128, 128, 64, true ><<<dim3(2, N/128), blk, 0, stream>>>(
        xqb, nullptr, wd0, nullptr, db0, h2b, nullptr, (int)N, 256, 64);
    mm_mfma<short, false, 2, 128, 128, 64, true ><<<dim3(4, N/128), blk, 0, stream>>>(
        h2b, nullptr, wd1, nullptr, db1, h1b, nullptr, (int)N, 512, 256);
    mm_mfma<short, false, 0, 128, 128, 64, false><<<dim3(6, N/128), blk, 0, stream>>>(
        h1b, nullptr, wd2, nullptr, db2, out, nullptr, (int)N, 768, 512);
}